// Round 2
// baseline (135.588 us; speedup 1.0000x reference)
//
#include <hip/hip_runtime.h>
#include <math.h>

constexpr int C = 20;   // classes
constexpr int M = 32;   // max GT per image
#define LN2F 0.69314718055994530942f

// Broadcast one GT component (held in lanes 0..31 of a VGPR) to an SGPR.
// v_readlane is full-rate VALU with a uniform (SGPR) result, so the IoU math
// below runs as (VGPR op SGPR) with ZERO LDS traffic in the hot loop.
// R1 lesson: the readlane loop itself is fine — the regression came from
// KPA=2 + double cls prefetch (~50 extra live VGPRs -> occupancy cliff).
__device__ __forceinline__ float rl(float v, int j) {
    return __int_as_float(__builtin_amdgcn_readlane(__float_as_int(v), j));
}

// d_ws layout: part[(b*nblk + bx)*4 + {0,1,2}] = {cls_sum, reg_sum, num_pos}
// per block. Plain stores — NO atomics (R12/R13 lesson: device-scope atomicAdd
// to 2 cache lines serializes at ~28 cyc each; 11K atomics == 135 us).
__global__ __launch_bounds__(256) void focal_main(
    const float* __restrict__ cls,   // [B,A,C]
    const float* __restrict__ reg,   // [B,A,4]
    const float* __restrict__ anc,   // [A,4]
    const float* __restrict__ ann,   // [B,M,5]
    float* __restrict__ part,
    int A)
{
    __shared__ float4 s_gbox[M];   // compacted valid GT; tail slots zero-box
    __shared__ int    s_glbl[M];
    __shared__ int    s_cnt;
    __shared__ float  s_red[4 * 3];

    const int b   = blockIdx.y;
    const int tid = threadIdx.x;

    // ---- stage + ORDER-PRESERVING compaction of valid GT (wave 0 only).
    //      prefix-popcount keeps reference argmax first-tie semantics.
    //      Clear-then-scatter is race-free: both are wave-ordered ds_writes. ----
    if (tid < 64) {
        bool  v  = false;
        float x1 = 0.f, y1 = 0.f, x2 = 0.f, y2 = 0.f, lb = -1.f;
        if (tid < M) {
            const float* ap = ann + (size_t)b * M * 5 + (size_t)tid * 5;
            x1 = ap[0]; y1 = ap[1]; x2 = ap[2]; y2 = ap[3]; lb = ap[4];
            v = (lb != -1.0f);
            s_gbox[tid] = make_float4(0.f, 0.f, 0.f, 0.f);
            s_glbl[tid] = 0;
        }
        const unsigned long long mask = __ballot(v);
        if (v) {
            const int pos = __popcll(mask & ((1ull << tid) - 1ull));
            s_gbox[pos] = make_float4(x1, y1, x2, y2);
            s_glbl[pos] = (int)lb;
        }
        if (tid == 0) s_cnt = (int)__popcll(mask);
    }
    __syncthreads();

    // ---- per-wave GT register copy: lanes 0..31 hold compacted GT 0..31.
    //      ONE ds_read_b128 per thread; the IoU loop does NO LDS ops
    //      (round-0: 32 x (b128+b32) broadcast reads = ~570 LDS-pipe
    //      cycles/wave on the serializing return path). ----
    const float4 gb    = s_gbox[tid & 31];
    const float  garea = (gb.z - gb.x) * (gb.w - gb.y);
    const int    cnt   = __builtin_amdgcn_readfirstlane(s_cnt); // uniform bound

    const int a = blockIdx.x * 256 + tid;

    float clsSum = 0.f, regSum = 0.f, posf = 0.f;

    if (a < A) {
        const float4 av = *(const float4*)(anc + (size_t)a * 4);
        const float aw  = av.z - av.x;
        const float ah  = av.w - av.y;
        const float area_a = aw * ah;

        // ---- prefetch the cls row BEFORE the IoU loop (T14): 5 dwordx4
        //      issue ~700 cycles before first use, HBM/L2 latency hides under
        //      the IoU math. Costs 20 VGPRs — peak live set ~105, stays under
        //      the 128-VGPR occupancy cliff (the R1 mistake was 2 rows = 40). ----
        const float* cp = cls + ((size_t)b * A + a) * C;
        float4 cv[C / 4];
        #pragma unroll
        for (int k = 0; k < C / 4; ++k) cv[k] = ((const float4*)cp)[k];

        // ---- IoU argmax, division-free, LDS-free: best kept as fraction
        //      (n_b/d_b); n_j*d_b > n_b*d_j replaces rcp+mul per GT. GT
        //      broadcast via 5 readlanes/GT; uniform trip count = compacted
        //      valid GT (28/32 here -> 12.5% fewer iterations). ----
        float n_b = -1.0f, d_b = 1.0f;
        int   bi = 0;
        #pragma unroll 4
        for (int j = 0; j < cnt; ++j) {
            const float gx1 = rl(gb.x, j);
            const float gy1 = rl(gb.y, j);
            const float gx2 = rl(gb.z, j);
            const float gy2 = rl(gb.w, j);
            const float gab = rl(garea, j);
            const float iw = fmaxf(fminf(av.z, gx2) - fmaxf(av.x, gx1), 0.f);
            const float ih = fmaxf(fminf(av.w, gy2) - fmaxf(av.y, gy1), 0.f);
            const float inter = iw * ih;
            const float ua = fmaxf(area_a + gab - inter, 1e-8f);
            if (inter * d_b > n_b * ua) { n_b = inter; d_b = ua; bi = j; }
        }
        const float bv = n_b * __frcp_rn(d_b);    // value only for thresholds
        const bool pos    = bv >= 0.5f;
        const bool ignore = (bv >= 0.4f) && !pos;

        // ---- classification focal loss: negative-form sum in log2 space.
        //      cls = 0.8*ln2 * sum(p^1.5 * -log2(1-p)) (+ pos correction). ----
        if (!ignore) {
            float sum = 0.f;                      // in log2 units
            #pragma unroll
            for (int k = 0; k < C / 4; ++k) {
                const float4 v4 = cv[k];
                const float pv4[4] = {v4.x, v4.y, v4.z, v4.w};
                #pragma unroll
                for (int u = 0; u < 4; ++u) {
                    const float p = fminf(fmaxf(pv4[u], 1e-8f), 1.0f - 1e-8f);
                    sum += p * __builtin_amdgcn_sqrtf(p) * (-__log2f(1.0f - p));
                }
            }
            sum *= 0.8f;
            if (pos) {                            // swap in the label-class term
                // positives are rare: one L1-hot scattered load beats a
                // 20-long cndmask chain executed by EVERY anchor. Runtime
                // indexing into cv[] would spill to scratch (rule #20).
                const int   lbl = s_glbl[bi];
                const float p_t = fminf(fmaxf(cp[lbl], 1e-8f), 1.0f - 1e-8f);
                const float q   = 1.0f - p_t;
                sum -= 0.8f * p_t * __builtin_amdgcn_sqrtf(p_t) * (-__log2f(q));
                sum += 0.2f * q   * __builtin_amdgcn_sqrtf(q)   * (-__log2f(p_t));
            }
            clsSum = sum * LN2F;
        }

        // ---- regression smooth-L1 (positives only; reg loads stay inside
        //      the branch: most waves have 0 positives -> lines never fetched,
        //      ~15 MB of HBM traffic avoided). ----
        if (pos) {
            posf = 1.0f;
            const float acx = av.x + 0.5f * aw;
            const float acy = av.y + 0.5f * ah;
            const float4 g = s_gbox[bi];
            const float gwr = g.z - g.x, ghr = g.w - g.y;
            const float gcx = g.x + 0.5f * gwr, gcy = g.y + 0.5f * ghr;
            const float gw = fmaxf(gwr, 1.f), gh = fmaxf(ghr, 1.f);
            float rt[4];
            rt[0] = ((gcx - acx) / aw) / 0.1f;
            rt[1] = ((gcy - acy) / ah) / 0.1f;
            rt[2] = __logf(gw / aw) / 0.2f;
            rt[3] = __logf(gh / ah) / 0.2f;
            const float4 rv = *(const float4*)(reg + ((size_t)b * A + a) * 4);
            const float rr[4] = {rv.x, rv.y, rv.z, rv.w};
            #pragma unroll
            for (int u = 0; u < 4; ++u) {
                const float d = fabsf(rt[u] - rr[u]);
                regSum += (d <= (float)(1.0 / 9.0)) ? (4.5f * d * d)
                                                    : (d - (float)(0.5 / 9.0));
            }
        }
    }

    // ---- block reduce: wave shuffle -> cross-wave LDS -> ONE plain store ----
    #pragma unroll
    for (int off = 32; off > 0; off >>= 1) {
        clsSum += __shfl_down(clsSum, off, 64);
        regSum += __shfl_down(regSum, off, 64);
        posf   += __shfl_down(posf,   off, 64);
    }
    const int wave = tid >> 6;
    const int lane = tid & 63;
    if (lane == 0) {
        s_red[wave*3+0] = clsSum;
        s_red[wave*3+1] = regSum;
        s_red[wave*3+2] = posf;
    }
    __syncthreads();
    if (tid == 0) {
        float cs = 0.f, rs = 0.f, ps = 0.f;
        #pragma unroll
        for (int w2 = 0; w2 < 4; ++w2) {
            cs += s_red[w2*3+0];
            rs += s_red[w2*3+1];
            ps += s_red[w2*3+2];
        }
        const size_t slot = ((size_t)b * gridDim.x + blockIdx.x) * 4;
        *(float4*)(part + slot) = make_float4(cs, rs, ps, 0.f);
    }
}

// Tree-reduce the B x nblk partial triplets + final normalization.
// 1024 threads: 128 threads per image (B=8).
__global__ __launch_bounds__(1024) void focal_final(
    const float* __restrict__ part,
    const float* __restrict__ ann,
    float* __restrict__ out, int B, int nblk)
{
    __shared__ float s_sum[8][2][3];   // [image][wave-in-group][{cls,reg,pos}]
    __shared__ float s_f[256];
    __shared__ float s_c[8], s_r[8];

    const int tid = threadIdx.x;
    const int g   = tid >> 7;          // image 0..7
    const int i   = tid & 127;

    float cs = 0.f, rs = 0.f, ps = 0.f;
    if (g < B) {
        for (int bx = i; bx < nblk; bx += 128) {
            const float4 v = *(const float4*)(part + ((size_t)g * nblk + bx) * 4);
            cs += v.x; rs += v.y; ps += v.z;
        }
    }
    #pragma unroll
    for (int off = 32; off > 0; off >>= 1) {
        cs += __shfl_down(cs, off, 64);
        rs += __shfl_down(rs, off, 64);
        ps += __shfl_down(ps, off, 64);
    }
    const int lane = tid & 63;
    const int wv   = (tid >> 6) & 1;   // wave within the 128-thread group
    if (lane == 0 && g < 8) {
        s_sum[g][wv][0] = cs; s_sum[g][wv][1] = rs; s_sum[g][wv][2] = ps;
    }

    // GT validity flags in parallel (B*M = 256)
    if (tid < 256) {
        float f = 0.f;
        if (tid < B * M) {
            const int bb = tid >> 5, j = tid & 31;
            f = (ann[(size_t)bb * M * 5 + (size_t)j * 5 + 4] != -1.0f) ? 1.f : 0.f;
        }
        s_f[tid] = f;
    }
    __syncthreads();

    if (tid < B) {
        const float S  = s_sum[tid][0][0] + s_sum[tid][1][0];
        const float R  = s_sum[tid][0][1] + s_sum[tid][1][1];
        const float np = s_sum[tid][0][2] + s_sum[tid][1][2];
        float nv = 0.f;
        #pragma unroll
        for (int j = 0; j < M; ++j) nv += s_f[tid * M + j];
        float cl  = S / fmaxf(np, 1.f);
        float rl2 = (np > 0.f) ? R / fmaxf(4.f * np, 1.f) : 0.f;
        if (nv == 0.f) { cl = 0.f; rl2 = 0.f; }
        s_c[tid] = cl; s_r[tid] = rl2;
    }
    __syncthreads();

    if (tid == 0) {
        float ca = 0.f, ra = 0.f;
        for (int b2 = 0; b2 < B; ++b2) { ca += s_c[b2]; ra += s_r[b2]; }
        out[0] = ca / (float)B;
        out[1] = ra / (float)B;
    }
}

extern "C" void kernel_launch(void* const* d_in, const int* in_sizes, int n_in,
                              void* d_out, int out_size, void* d_ws, size_t ws_size,
                              hipStream_t stream) {
    const float* cls = (const float*)d_in[0];   // [B,A,C]
    const float* reg = (const float*)d_in[1];   // [B,A,4]
    const float* anc = (const float*)d_in[2];   // [1,A,4]
    const float* ann = (const float*)d_in[3];   // [B,M,5]
    const int A = in_sizes[2] / 4;
    const int B = in_sizes[3] / (M * 5);
    const int nblk = (A + 255) / 256;           // 469 @ A=120000

    float* part = (float*)d_ws;   // B*nblk*4 floats (~60 KB); every slot is
                                  // written by focal_main, so no memset needed.

    dim3 grid(nblk, B);
    focal_main<<<grid, dim3(256), 0, stream>>>(cls, reg, anc, ann, part, A);
    focal_final<<<1, dim3(1024), 0, stream>>>(part, ann, (float*)d_out, B, nblk);
}

// Round 3
// 129.010 us; speedup vs baseline: 1.0510x; 1.0510x over previous
//
#include <hip/hip_runtime.h>
#include <math.h>

constexpr int C = 20;   // classes
constexpr int M = 32;   // max GT per image
#define LN2F 0.69314718055994530942f

// d_ws layout: part[(b*nblk + bx)*4 + {0,1,2}] = {cls_sum, reg_sum, num_pos}
// per block. Plain stores — NO atomics (R12/R13 lesson: device-scope atomicAdd
// to 2 cache lines serializes at ~28 cyc each; 11K atomics == 135 us).
//
// R1/R2 lesson: wave-uniform LDS broadcast reads in the IoU loop are nearly
// free (same-address ds_read = broadcast, no per-lane return cost) — replacing
// them with v_readlane (serial VALU->SGPR with RAW hazards) cost +8 us. This
// is the measured-best R0 structure with ONE change: cls rows prefetched
// before the IoU loop so their HBM latency hides under the IoU VALU.
__global__ __launch_bounds__(256) void focal_main(
    const float* __restrict__ cls,   // [B,A,C]
    const float* __restrict__ reg,   // [B,A,4]
    const float* __restrict__ anc,   // [A,4]
    const float* __restrict__ ann,   // [B,M,5]
    float* __restrict__ part,
    int A)
{
    __shared__ float4 s_gbox[M];   // {x1,y1,x2,y2}; invalid GT -> zero box (iou=0)
    __shared__ float  s_garea[M];
    __shared__ int    s_glbl[M];
    __shared__ float  s_red[4 * 3];

    const int b   = blockIdx.y;
    const int tid = threadIdx.x;

    // ---- stage annotations (validity folded: 2 LDS reads/GT in IoU loop) ----
    if (tid < M) {
        const float* ap = ann + (size_t)b * M * 5 + (size_t)tid * 5;
        float x1 = ap[0], y1 = ap[1], x2 = ap[2], y2 = ap[3];
        const float lb = ap[4];
        s_glbl[tid] = (int)lb;
        if (lb == -1.0f) { x1 = 0.f; y1 = 0.f; x2 = 0.f; y2 = 0.f; }
        s_gbox[tid]  = make_float4(x1, y1, x2, y2);
        s_garea[tid] = (x2 - x1) * (y2 - y1);
    }
    __syncthreads();

    const int a = blockIdx.x * 256 + tid;

    float clsSum = 0.f, regSum = 0.f, posf = 0.f;

    if (a < A) {
        const float4 av = *(const float4*)(anc + (size_t)a * 4);
        const float aw  = av.z - av.x;
        const float ah  = av.w - av.y;
        const float acx = av.x + 0.5f * aw;
        const float acy = av.y + 0.5f * ah;
        const float area_a = aw * ah;

        // ---- THE ONE CHANGE vs R0: prefetch the cls row before the IoU
        //      loop. 5 dwordx4 issue ~1100 VALU-cycles before first use, so
        //      the ~700-cyc HBM latency is hidden by ILP instead of being
        //      exposed at the s_waitcnt right after issue. Cost: +20 live
        //      VGPRs (~80 -> ~100, waves/SIMD 6 -> 5; no 128 cliff). ----
        const float* cp = cls + ((size_t)b * A + a) * C;
        float4 cv[C / 4];
        #pragma unroll
        for (int k = 0; k < C / 4; ++k) cv[k] = ((const float4*)cp)[k];

        // ---- IoU argmax, division-free: best kept as fraction (n_b/d_b).
        //      n_j*d_b > n_b*d_j replaces rcp+mul per GT (one rcp per anchor).
        //      unroll 8: full 32-unroll batched ds_reads -> VGPR 80, occ 25%. ----
        float n_b = -1.0f, d_b = 1.0f;
        int   bi = 0;
        #pragma unroll 8
        for (int j = 0; j < M; ++j) {
            const float4 g  = s_gbox[j];
            const float  ab = s_garea[j];
            const float iw = fmaxf(fminf(av.z, g.z) - fmaxf(av.x, g.x), 0.f);
            const float ih = fmaxf(fminf(av.w, g.w) - fmaxf(av.y, g.y), 0.f);
            const float inter = iw * ih;
            const float ua = fmaxf(area_a + ab - inter, 1e-8f);
            if (inter * d_b > n_b * ua) { n_b = inter; d_b = ua; bi = j; }
        }
        const float bv = n_b * __frcp_rn(d_b);    // value only for thresholds
        const bool pos    = bv >= 0.5f;
        const bool ignore = (bv >= 0.4f) && !pos;
        const int  lbl    = s_glbl[bi];           // in [0,19] whenever pos

        // ---- classification focal loss: negative-form sum in log2 space.
        //      cls = 0.8*ln2 * sum(p^1.5 * -log2(1-p)) (+ pos correction). ----
        if (!ignore) {
            float sum = 0.f;                      // in log2 units
            float p_t = 0.5f;                     // label-class prob (pos only)
            #pragma unroll
            for (int k = 0; k < C / 4; ++k) {
                const float4 v = cv[k];
                const float pv4[4] = {v.x, v.y, v.z, v.w};
                #pragma unroll
                for (int u = 0; u < 4; ++u) {
                    const int c = k * 4 + u;
                    const float p = fminf(fmaxf(pv4[u], 1e-8f), 1.0f - 1e-8f);
                    sum += p * __builtin_amdgcn_sqrtf(p) * (-__log2f(1.0f - p));
                    p_t = (c == lbl) ? p : p_t;   // one cndmask per class
                }
            }
            sum *= 0.8f;
            if (pos) {                            // swap in the label-class term
                const float q = 1.0f - p_t;
                sum -= 0.8f * p_t * __builtin_amdgcn_sqrtf(p_t) * (-__log2f(q));
                sum += 0.2f * q   * __builtin_amdgcn_sqrtf(q)   * (-__log2f(p_t));
            }
            clsSum = sum * LN2F;
        }

        // ---- regression smooth-L1 (positives only) ----
        if (pos) {
            posf = 1.0f;
            const float4 g = s_gbox[bi];
            const float gwr = g.z - g.x, ghr = g.w - g.y;
            const float gcx = g.x + 0.5f * gwr, gcy = g.y + 0.5f * ghr;
            const float gw = fmaxf(gwr, 1.f), gh = fmaxf(ghr, 1.f);
            float rt[4];
            rt[0] = ((gcx - acx) / aw) / 0.1f;
            rt[1] = ((gcy - acy) / ah) / 0.1f;
            rt[2] = __logf(gw / aw) / 0.2f;
            rt[3] = __logf(gh / ah) / 0.2f;
            const float4 rv = *(const float4*)(reg + ((size_t)b * A + a) * 4);
            const float rr[4] = {rv.x, rv.y, rv.z, rv.w};
            #pragma unroll
            for (int u = 0; u < 4; ++u) {
                const float d = fabsf(rt[u] - rr[u]);
                regSum += (d <= (float)(1.0 / 9.0)) ? (4.5f * d * d)
                                                    : (d - (float)(0.5 / 9.0));
            }
        }
    }

    // ---- block reduce: wave shuffle -> cross-wave LDS -> ONE plain store ----
    #pragma unroll
    for (int off = 32; off > 0; off >>= 1) {
        clsSum += __shfl_down(clsSum, off, 64);
        regSum += __shfl_down(regSum, off, 64);
        posf   += __shfl_down(posf,   off, 64);
    }
    const int wave = tid >> 6;
    const int lane = tid & 63;
    if (lane == 0) {
        s_red[wave*3+0] = clsSum;
        s_red[wave*3+1] = regSum;
        s_red[wave*3+2] = posf;
    }
    __syncthreads();
    if (tid == 0) {
        float cs = 0.f, rs = 0.f, ps = 0.f;
        #pragma unroll
        for (int w2 = 0; w2 < 4; ++w2) {
            cs += s_red[w2*3+0];
            rs += s_red[w2*3+1];
            ps += s_red[w2*3+2];
        }
        const size_t slot = ((size_t)b * gridDim.x + blockIdx.x) * 4;
        *(float4*)(part + slot) = make_float4(cs, rs, ps, 0.f);
    }
}

// Tree-reduce the B x nblk partial triplets + final normalization.
// 1024 threads: 128 threads per image (B=8).
__global__ __launch_bounds__(1024) void focal_final(
    const float* __restrict__ part,
    const float* __restrict__ ann,
    float* __restrict__ out, int B, int nblk)
{
    __shared__ float s_sum[8][2][3];   // [image][wave-in-group][{cls,reg,pos}]
    __shared__ float s_f[256];
    __shared__ float s_c[8], s_r[8];

    const int tid = threadIdx.x;
    const int g   = tid >> 7;          // image 0..7
    const int i   = tid & 127;

    float cs = 0.f, rs = 0.f, ps = 0.f;
    if (g < B) {
        for (int bx = i; bx < nblk; bx += 128) {
            const float4 v = *(const float4*)(part + ((size_t)g * nblk + bx) * 4);
            cs += v.x; rs += v.y; ps += v.z;
        }
    }
    #pragma unroll
    for (int off = 32; off > 0; off >>= 1) {
        cs += __shfl_down(cs, off, 64);
        rs += __shfl_down(rs, off, 64);
        ps += __shfl_down(ps, off, 64);
    }
    const int lane = tid & 63;
    const int wv   = (tid >> 6) & 1;   // wave within the 128-thread group
    if (lane == 0 && g < 8) {
        s_sum[g][wv][0] = cs; s_sum[g][wv][1] = rs; s_sum[g][wv][2] = ps;
    }

    // GT validity flags in parallel (B*M = 256)
    if (tid < 256) {
        float f = 0.f;
        if (tid < B * M) {
            const int bb = tid >> 5, j = tid & 31;
            f = (ann[(size_t)bb * M * 5 + (size_t)j * 5 + 4] != -1.0f) ? 1.f : 0.f;
        }
        s_f[tid] = f;
    }
    __syncthreads();

    if (tid < B) {
        const float S  = s_sum[tid][0][0] + s_sum[tid][1][0];
        const float R  = s_sum[tid][0][1] + s_sum[tid][1][1];
        const float np = s_sum[tid][0][2] + s_sum[tid][1][2];
        float nv = 0.f;
        #pragma unroll
        for (int j = 0; j < M; ++j) nv += s_f[tid * M + j];
        float cl = S / fmaxf(np, 1.f);
        float rl = (np > 0.f) ? R / fmaxf(4.f * np, 1.f) : 0.f;
        if (nv == 0.f) { cl = 0.f; rl = 0.f; }
        s_c[tid] = cl; s_r[tid] = rl;
    }
    __syncthreads();

    if (tid == 0) {
        float ca = 0.f, ra = 0.f;
        for (int b2 = 0; b2 < B; ++b2) { ca += s_c[b2]; ra += s_r[b2]; }
        out[0] = ca / (float)B;
        out[1] = ra / (float)B;
    }
}

extern "C" void kernel_launch(void* const* d_in, const int* in_sizes, int n_in,
                              void* d_out, int out_size, void* d_ws, size_t ws_size,
                              hipStream_t stream) {
    const float* cls = (const float*)d_in[0];   // [B,A,C]
    const float* reg = (const float*)d_in[1];   // [B,A,4]
    const float* anc = (const float*)d_in[2];   // [1,A,4]
    const float* ann = (const float*)d_in[3];   // [B,M,5]
    const int A = in_sizes[2] / 4;
    const int B = in_sizes[3] / (M * 5);
    const int nblk = (A + 255) / 256;

    float* part = (float*)d_ws;   // B*nblk*4 floats (~60 KB); every slot is
                                  // written by focal_main, so no memset needed.

    dim3 grid(nblk, B);
    focal_main<<<grid, dim3(256), 0, stream>>>(cls, reg, anc, ann, part, A);
    focal_final<<<1, dim3(1024), 0, stream>>>(part, ann, (float*)d_out, B, nblk);
}